// Round 1
// baseline (67.359 us; speedup 1.0000x reference)
//
#include <hip/hip_runtime.h>
#include <hip/hip_bf16.h>

// Resonance synth: out(b,e,n) = sum_f env_f(n) * sin(2*pi*freq_f*(n+1))
//   freq_f = (MIN + SCALE*f0_be)*(f+1), aliased (>=1.0) harmonics contribute 0
//   env_f(n) = linear frame->sample interp of res^(t+1), 256 samples/frame.
//
// Round 7: packed-FP32 stride-2 Chebyshev.
//   Previous version: scalar Chebyshev s_{f+1} = 2cos(theta)*s_f - s_{f-1},
//   3 VALU per (harmonic, sample) -> 96 scalar VALU per k-step.
//   Now: stride-2 recurrence sin((f+2)t) = 2cos(2t)*sin(ft) - sin((f-2)t).
//   Odd/even chains share coefficient 2cos(2theta) -> pack (odd,even) pairs
//   into float2 and use v_pk_fma_f32 / v_pk_mul_f32 (VOP3P, gfx90a+):
//   16 packed fma (chain) + 16 packed fma (acc) + 16 packed mul (env)
//   = 48 instrs per k-step, half the issue slots of the scalar version.
//   sin/cos(2theta) from u32 phase doubling (qn<<1) -- exact mod-1 wrap.

#define NSAMP 32768
#define NFRM  128
#define NF    32
#define NP2   (NF / 2)           // 16 packed harmonic pairs
#define NPAIR 64
#define CHUNKS 16
#define CHUNK (NSAMP / CHUNKS)   // 2048 samples per block
#define KIT   (CHUNK / 256)      // 8 samples per thread, 8 frames per block

typedef __attribute__((ext_vector_type(2))) float f32x2;

__device__ __forceinline__ f32x2 pk_fma(f32x2 a, f32x2 b, f32x2 c) {
    return __builtin_elementwise_fma(a, b, c);
}

__device__ __forceinline__ float ldin(const void* p, int i, bool isbf) {
    if (isbf) {
        unsigned int w = ((unsigned int)((const unsigned short*)p)[i]) << 16;
        float f; __builtin_memcpy(&f, &w, 4); return f;
    }
    return ((const float*)p)[i];
}

// force a block-uniform float into an SGPR
__device__ __forceinline__ float rfl(float x) {
    int i; __builtin_memcpy(&i, &x, 4);
    i = __builtin_amdgcn_readfirstlane(i);
    float f; __builtin_memcpy(&f, &i, 4); return f;
}

extern "C" __global__ __launch_bounds__(256, 4)
void reson_kernel(const void* __restrict__ f0p,
                  const void* __restrict__ resp,
                  const void* __restrict__ facp,
                  void* __restrict__ outp)
{
    // dtype sniff: factors[0]==1.0f -> f32 word 0x3F800000; bf16 packs 0x40003F80
    const bool isbf = (((const unsigned int*)facp)[0] != 0x3F800000u);

    const int pair = blockIdx.x;             // 0..63
    const int y    = blockIdx.y;             // 0..15
    const int tid  = threadIdx.x;            // 0..255
    const int n0   = y * CHUNK + tid;

    const float MINF = (float)(40.0 / 11025.0);
    const float FSC  = (float)(3960.0 / 11025.0);

    __shared__ __align__(16) float sR[NF];
    __shared__ __align__(16) float sP[NF];   // r^(8y), alias-masked to 0

    const float f0v = rfl(ldin(f0p, pair, isbf));
    const float sf0 = MINF + FSC * f0v;      // < 0.37
    const unsigned int Q1 = (unsigned int)((double)sf0 * 4294967296.0 + 0.5);

    if (tid < NF) {
        const float r   = ldin(resp, pair * NF + tid, isbf);
        const float fac = ldin(facp, tid, isbf);
        float P = exp2f(log2f(r) * (float)(8 * y));   // r^(8y); y==0 -> 1
        if (sf0 * fac >= 1.0f) P = 0.0f;              // aliased harmonic
        sR[tid] = r;
        sP[tid] = P;
    }
    __syncthreads();

    const float c0raw = (n0 + 0.5f) * (1.0f / 256.0f) - 0.5f;
    // frame-endpoint exponent i0c+1 is 8y (lo half, y>0) or 8y+1 (hi half / y==0)
    const bool useR1 = (tid >= 128) || (y == 0);

    f32x2 E[NP2];    // per-thread env state, packed (harmonic 2j+1, 2j+2)
    f32x2 Rv[NP2];   // block-uniform decay factors
    #pragma unroll
    for (int j = 0; j < NP2; ++j) {
        const f32x2 p2 = *(const f32x2*)&sP[2 * j];  // ds_read_b64, broadcast
        const f32x2 r2 = *(const f32x2*)&sR[2 * j];
        Rv[j].x = rfl(r2.x); Rv[j].y = rfl(r2.y);
        E[j] = useR1 ? (f32x2)(p2 * Rv[j]) : p2;
    }

    const int obase = pair * NSAMP + n0;

    if (y != 0 && y != CHUNKS - 1) {
        // ---- interior: fold w0 once, then env_k = env_0 * r^k ----
        const float w0 = c0raw - floorf(c0raw);      // no clamps possible
        const f32x2 w0v = {w0, w0};
        #pragma unroll
        for (int j = 0; j < NP2; ++j) {
            const f32x2 M = E[j];
            E[j] = pk_fma(w0v, pk_fma(M, Rv[j], -M), M);  // M + w0*(M*r - M)
        }
        #pragma unroll 1
        for (int k = 0; k < KIT; ++k) {
            const unsigned int nn = (unsigned int)(n0 + (k << 8) + 1);
            const unsigned int qn = Q1 * nn;          // base phase, u32 turns
            const float t1 = (float)qn * 0x1p-32f;         // theta, revolutions
            const float t2 = (float)(qn << 1) * 0x1p-32f;  // 2*theta (exact wrap)
            const float s1 = __builtin_amdgcn_sinf(t1);
            const float s2 = __builtin_amdgcn_sinf(t2);
            const float c2 = __builtin_amdgcn_cosf(t2);
            const float k2s = c2 + c2;                // 2*cos(2*theta)
            const f32x2 k2 = {k2s, k2s};
            f32x2 sp = {-s1, 0.0f};                   // (sin(-theta), sin(0))
            f32x2 sc = {s1, s2};                      // (sin(theta), sin(2theta))
            f32x2 a0 = {0.0f, 0.0f}, a1 = {0.0f, 0.0f};
            #pragma unroll
            for (int j = 0; j < NP2; ++j) {
                if (j & 1) a1 = pk_fma(E[j], sc, a1);
                else       a0 = pk_fma(E[j], sc, a0);
                E[j] = E[j] * Rv[j];
                const f32x2 sn = pk_fma(k2, sc, -sp); // sin((f+2)theta) pair
                sp = sc; sc = sn;
            }
            const f32x2 as = a0 + a1;
            const float acc = as.x + as.y;
            const int o = obase + (k << 8);
            if (isbf) ((__hip_bfloat16*)outp)[o] = __float2bfloat16(acc);
            else      ((float*)outp)[o] = acc;
        }
    } else {
        // ---- edge blocks (y==0 clamp-low, y==15 clamp-high): general interp ----
        const float c0 = fminf(fmaxf(c0raw, 0.0f), 127.0f);
        const float w0 = c0 - floorf(c0);
        const float c1e = c0raw + 1.0f;
        const float w1 = c1e - floorf(c1e);
        const bool clampLow = (y == 0) && (c0raw < 0.0f);
        #pragma unroll 1
        for (int k = 0; k < KIT; ++k) {
            const unsigned int nn = (unsigned int)(n0 + (k << 8) + 1);
            const unsigned int qn = Q1 * nn;
            const float t1 = (float)qn * 0x1p-32f;
            const float t2 = (float)(qn << 1) * 0x1p-32f;
            const float s1 = __builtin_amdgcn_sinf(t1);
            const float s2 = __builtin_amdgcn_sinf(t2);
            const float c2 = __builtin_amdgcn_cosf(t2);
            const float k2s = c2 + c2;
            const f32x2 k2 = {k2s, k2s};
            f32x2 sp = {-s1, 0.0f};
            f32x2 sc = {s1, s2};
            const float wk = (k == 0)
                ? w0 : ((c0raw + (float)k > 127.0f) ? 0.0f : w1);
            const f32x2 wkv = {wk, wk};
            const bool adv = !((k == 0) && clampLow); // clamped lanes hold frame 0
            f32x2 a0 = {0.0f, 0.0f}, a1 = {0.0f, 0.0f};
            #pragma unroll
            for (int j = 0; j < NP2; ++j) {
                const f32x2 M   = E[j];
                const f32x2 An  = M * Rv[j];
                const f32x2 env = pk_fma(wkv, An - M, M);
                if (j & 1) a1 = pk_fma(env, sc, a1);
                else       a0 = pk_fma(env, sc, a0);
                E[j] = adv ? An : M;
                const f32x2 sn = pk_fma(k2, sc, -sp);
                sp = sc; sc = sn;
            }
            const f32x2 as = a0 + a1;
            const float acc = as.x + as.y;
            const int o = obase + (k << 8);
            if (isbf) ((__hip_bfloat16*)outp)[o] = __float2bfloat16(acc);
            else      ((float*)outp)[o] = acc;
        }
    }
}

extern "C" void kernel_launch(void* const* d_in, const int* in_sizes, int n_in,
                              void* d_out, int out_size, void* d_ws, size_t ws_size,
                              hipStream_t stream) {
    (void)in_sizes; (void)n_in; (void)out_size; (void)d_ws; (void)ws_size;
    dim3 grid(NPAIR, CHUNKS);   // 64 x 16 = 1024 blocks = 4 blocks/CU, tail-free
    dim3 block(256);
    reson_kernel<<<grid, block, 0, stream>>>(d_in[0], d_in[1], d_in[2], d_out);
}